// Round 10
// baseline (761.580 us; speedup 1.0000x reference)
//
#include <hip/hip_runtime.h>
#include <hip/hip_bf16.h>
#include <math.h>

#define N_NODES 50000
#define E_MSG   800000
#define E_FULL  1000000
#define IN_C    128
#define H_C     64
#define T_STEPS 128

// ---- workspace layout (in floats) ----
#define OFF_Win   0
#define OFF_bin   8192
#define OFF_Wt1   8256
#define OFF_bt1   24640
#define OFF_Wt2   24896
#define OFF_bt2   41280
#define OFF_Wc0   41344
#define OFF_bc0   45440
#define OFF_Wc1   45504
#define OFF_bc1   49600
#define OFF_Wd1   49664
#define OFF_bd1   57856
#define OFF_Wd2   57920
#define OFF_bd2   57984
#define W_TOTAL   57985
#define OFF_BSUM  58016                 // 256 ints (bucket exclusive prefixes)
#define OFF_BCUR  58272                 // 256 ints (bucket fill cursors)
#define OFF_FWD1  58624                 // 8192 fp8 bytes (16*Wd1 frag table)
#define OFF_FWIN  60672                 // 8192 bf16 (W_in frag table)
#define OFF_FWC0  64768                 // 4096 bf16 (Wc0 frag table)
#define OFF_TEMB  66816                 // 128*64 floats
#define OFF_DINV  75008                 // 50000 floats
#define OFF_CNT   125008                // 50000 ints
#define OFF_PTR   175008                // 50001 ints
#define OFF_ELIST 225010                // 800000 ints
#define OFF_TMP   1025010               // pad to even below
#define OFF_TMP2  1025012               // 1.6M ints (800000 uint2), 8B aligned
#define OFF_ZBF   2625012               // 3.2M bf16 (z0)
#define OFF_ZBF2  4225012               // 3.2M bf16 (z1)
#define OFF_HENC8 5825012               // 3.2M fp8 bytes
// total 6,625,012 floats = 26.5 MB

#define SCAN_NB   ((N_NODES + 255) / 256)   // 196

typedef __attribute__((ext_vector_type(8))) short bf16x8;
typedef __attribute__((ext_vector_type(4))) float f32x4;

static __device__ __forceinline__ float bf2f(unsigned short u) {
    return __uint_as_float(((unsigned)u) << 16);
}
static __device__ __forceinline__ unsigned short f2bf(float f) {
    unsigned u = __float_as_uint(f);
    unsigned r = (u + 0x7fffu + ((u >> 16) & 1u)) >> 16;
    return (unsigned short)r;
}
// fp32 -> fp8 e4m3fn, RNE, clamp to +-448
static __device__ __forceinline__ unsigned char f2fp8(float f) {
    unsigned u = __float_as_uint(f);
    unsigned s = (u >> 24) & 0x80;
    float a = fminf(__uint_as_float(u & 0x7FFFFFFF), 448.0f);
    if (a < 0.015625f) {
        int qi = (int)rintf(a * 512.0f);
        return (unsigned char)(s | qi);
    }
    unsigned ua = __float_as_uint(a);
    int e = (int)((ua >> 23) & 0xFF) - 127;
    unsigned man = (ua & 0x7FFFFF) | 0x800000;
    unsigned r = man >> 20;
    unsigned rem = man & 0xFFFFF;
    if (rem > 0x80000u || (rem == 0x80000u && (r & 1))) r++;
    if (r == 16) { r = 8; e++; }
    if (e > 8) return (unsigned char)(s | 0x7E);
    return (unsigned char)(s | ((unsigned)(e + 7) << 3) | (r & 7));
}
static __device__ __forceinline__ bool detect_f32(const unsigned short* w, int* scnt) {
    if (threadIdx.x == 0) *scnt = 0;
    __syncthreads();
    int big = 0;
    for (int i = threadIdx.x; i < 2048; i += blockDim.x)
        if (fabsf(bf2f(w[2 * i])) > 0.5f) big++;
    atomicAdd(scnt, big);
    __syncthreads();
    return *scnt > 64;
}

// ---------------- weight conversion -> fp32, packed ----------------
struct CvtArgs { const void* src[14]; };

__global__ void k_cvt(CvtArgs a, float* ws) {
    __shared__ int scnt;
    bool f32 = detect_f32((const unsigned short*)a.src[0], &scnt);
    int t = blockIdx.x * 256 + threadIdx.x;
    if (t >= W_TOTAL) return;
    const int starts[14] = {OFF_Win, OFF_bin, OFF_Wt1, OFF_bt1, OFF_Wt2, OFF_bt2,
                            OFF_Wc0, OFF_bc0, OFF_Wc1, OFF_bc1, OFF_Wd1, OFF_bd1,
                            OFF_Wd2, OFF_bd2};
    int seg = 0;
#pragma unroll
    for (int i = 1; i < 14; i++)
        if (t >= starts[i]) seg = i;
    int off = t - starts[seg];
    ws[t] = f32 ? ((const float*)a.src[seg])[off]
                : bf2f(((const unsigned short*)a.src[seg])[off]);
}

// ---------------- MFMA B-fragment tables ----------------
__global__ void __launch_bounds__(256) k_prep(float* ws) {
    int idx = blockIdx.x * 256 + threadIdx.x;      // 0..20479
    int local, j, lane, ct, c, t, m, q;
    if (idx < 8192) {
        local = idx;
        j = local & 7; lane = (local >> 3) & 63; ct = local >> 9;
        c = ct >> 2; t = ct & 3; m = lane & 15; q = lane >> 4;
        ((unsigned char*)(ws + OFF_FWD1))[local] =
            f2fp8(16.0f * ws[OFF_Wd1 + (32 * c + 8 * q + j) * 64 + 16 * t + m]);
    } else if (idx < 16384) {
        local = idx - 8192;
        j = local & 7; lane = (local >> 3) & 63; ct = local >> 9;
        c = ct >> 2; t = ct & 3; m = lane & 15; q = lane >> 4;
        ((unsigned short*)(ws + OFF_FWIN))[local] =
            f2bf(ws[OFF_Win + (32 * c + 8 * q + j) * 64 + 16 * t + m]);
    } else if (idx < 20480) {
        local = idx - 16384;
        j = local & 7; lane = (local >> 3) & 63; ct = local >> 9;
        c = ct >> 2; t = ct & 3; m = lane & 15; q = lane >> 4;
        ((unsigned short*)(ws + OFF_FWC0))[local] =
            f2bf(ws[OFF_Wc0 + (32 * c + 8 * q + j) * 64 + 16 * t + m]);
    }
}

// ---------------- t_emb table ----------------
__global__ void __launch_bounds__(64) k_temb(float* ws) {
    const float* Wt1 = ws + OFF_Wt1;
    const float* bt1 = ws + OFF_bt1;
    const float* Wt2 = ws + OFF_Wt2;
    const float* bt2 = ws + OFF_bt2;
    float* temb = ws + OFF_TEMB;
    int t = blockIdx.x;
    int j = threadIdx.x;

    __shared__ float pe[64];
    __shared__ float us[256];

    float xt = (float)t * (4000.0f / 128.0f);
    float sc = -logf(10000.0f) / 31.0f;
    int idx = j & 31;
    float fr = __expf((float)idx * sc);
    float ang = xt * fr;
    pe[j] = (j < 32) ? sinf(ang) : cosf(ang);
    __syncthreads();

    float u[4];
#pragma unroll
    for (int q = 0; q < 4; q++) u[q] = bt1[q * 64 + j];
    for (int k = 0; k < 64; k++) {
        float p = pe[k];
#pragma unroll
        for (int q = 0; q < 4; q++)
            u[q] = fmaf(p, Wt1[k * 256 + q * 64 + j], u[q]);
    }
#pragma unroll
    for (int q = 0; q < 4; q++) {
        float uu = u[q];
        us[q * 64 + j] = uu * __builtin_amdgcn_rcpf(1.0f + __expf(-uu));
    }
    __syncthreads();

    float acc = bt2[j];
    for (int k = 0; k < 256; k++)
        acc = fmaf(us[k], Wt2[k * 64 + j], acc);
    temb[t * 64 + j] = acc;
}

// ---------------- embedder + fused GCN-linear-0 (MFMA x2) ----------------
__global__ void __launch_bounds__(256) k_embed(const void* __restrict__ xraw,
                                               const unsigned short* __restrict__ wdet,
                                               const int* __restrict__ tsteps,
                                               float* __restrict__ ws,
                                               float* __restrict__ out_hembed,
                                               unsigned short* __restrict__ zbf) {
    __shared__ int scnt;
    __shared__ unsigned short tl[4][16 * 64];
    bool f32 = detect_f32(wdet, &scnt);

    int lane = threadIdx.x & 63;
    int wv = threadIdx.x >> 6;
    int m = lane & 15, quad = lane >> 4;
    int wid = blockIdx.x * 4 + wv;
    if (wid > N_NODES / 16 - 1) wid = N_NODES / 16 - 1;   // clamp (dup work benign)
    int n0 = wid * 16;

    const unsigned short* fwin = (const unsigned short*)(ws + OFF_FWIN);
    const unsigned short* fwc0 = (const unsigned short*)(ws + OFF_FWC0);

    bf16x8 bI[4][4];
#pragma unroll
    for (int c = 0; c < 4; c++)
#pragma unroll
        for (int t = 0; t < 4; t++)
            bI[c][t] = *reinterpret_cast<const bf16x8*>(fwin + (c * 4 + t) * 512 + lane * 8);

    f32x4 acc[4] = {f32x4{0,0,0,0}, f32x4{0,0,0,0}, f32x4{0,0,0,0}, f32x4{0,0,0,0}};
#pragma unroll
    for (int c = 0; c < 4; c++) {
        bf16x8 a;
        if (f32) {
            const float* xp = (const float*)xraw + (size_t)(n0 + m) * 128 + 32 * c + 8 * quad;
            float4 v0 = *reinterpret_cast<const float4*>(xp);
            float4 v1 = *reinterpret_cast<const float4*>(xp + 4);
            a[0] = (short)f2bf(v0.x); a[1] = (short)f2bf(v0.y);
            a[2] = (short)f2bf(v0.z); a[3] = (short)f2bf(v0.w);
            a[4] = (short)f2bf(v1.x); a[5] = (short)f2bf(v1.y);
            a[6] = (short)f2bf(v1.z); a[7] = (short)f2bf(v1.w);
        } else {
            a = *reinterpret_cast<const bf16x8*>(
                (const unsigned short*)xraw + (size_t)(n0 + m) * 128 + 32 * c + 8 * quad);
        }
#pragma unroll
        for (int t = 0; t < 4; t++)
            acc[t] = __builtin_amdgcn_mfma_f32_16x16x32_bf16(a, bI[c][t], acc[t], 0, 0, 0);
    }

    int tn[4];
#pragma unroll
    for (int r = 0; r < 4; r++) tn[r] = tsteps[n0 + 4 * quad + r];
    const float* temb = ws + OFF_TEMB;
#pragma unroll
    for (int t = 0; t < 4; t++) {
        int ch = 16 * t + m;
        float bj = ws[OFF_bin + ch];
#pragma unroll
        for (int r = 0; r < 4; r++) {
            int node = n0 + 4 * quad + r;
            float v = acc[t][r] + bj + temb[tn[r] * 64 + ch];
            out_hembed[(size_t)node * 64 + ch] = v;
            tl[wv][(4 * quad + r) * 64 + ch] = f2bf(v);
        }
    }
    __syncthreads();

    bf16x8 bC[2][4];
#pragma unroll
    for (int c = 0; c < 2; c++)
#pragma unroll
        for (int t = 0; t < 4; t++)
            bC[c][t] = *reinterpret_cast<const bf16x8*>(fwc0 + (c * 4 + t) * 512 + lane * 8);

    f32x4 az[4] = {f32x4{0,0,0,0}, f32x4{0,0,0,0}, f32x4{0,0,0,0}, f32x4{0,0,0,0}};
#pragma unroll
    for (int c = 0; c < 2; c++) {
        bf16x8 a2 = *reinterpret_cast<const bf16x8*>(&tl[wv][m * 64 + 32 * c + 8 * quad]);
#pragma unroll
        for (int t = 0; t < 4; t++)
            az[t] = __builtin_amdgcn_mfma_f32_16x16x32_bf16(a2, bC[c][t], az[t], 0, 0, 0);
    }
    const float* dinv = ws + OFF_DINV;
    float dv[4];
#pragma unroll
    for (int r = 0; r < 4; r++) dv[r] = dinv[n0 + 4 * quad + r];
#pragma unroll
    for (int t = 0; t < 4; t++) {
        int ch = 16 * t + m;
#pragma unroll
        for (int r = 0; r < 4; r++)
            zbf[(size_t)(n0 + 4 * quad + r) * 64 + ch] = f2bf(az[t][r] * dv[r]);
    }
}

// ---------------- CSR build ----------------
__global__ void k_count(const int* __restrict__ col, int* __restrict__ cnt) {
    int t = blockIdx.x * 256 + threadIdx.x;
    if (t < E_MSG) atomicAdd(&cnt[col[t]], 1);
}

__global__ void __launch_bounds__(256) k_scan1(const int* __restrict__ cnt,
                                               int* __restrict__ bsum) {
    __shared__ int s[256];
    int n = blockIdx.x * 256 + threadIdx.x;
    s[threadIdx.x] = (n < N_NODES) ? cnt[n] : 0;
    __syncthreads();
    for (int off = 128; off > 0; off >>= 1) {
        if (threadIdx.x < off) s[threadIdx.x] += s[threadIdx.x + off];
        __syncthreads();
    }
    if (threadIdx.x == 0) bsum[blockIdx.x] = s[0];
}

__global__ void __launch_bounds__(256) k_scan2(int* __restrict__ bsum,
                                               int* __restrict__ bcur,
                                               int* __restrict__ ptr) {
    __shared__ int s[256];
    int t = threadIdx.x;
    int v = (t < SCAN_NB) ? bsum[t] : 0;
    s[t] = v;
    __syncthreads();
    for (int off = 1; off < 256; off <<= 1) {
        int u = (t >= off) ? s[t - off] : 0;
        __syncthreads();
        s[t] += u;
        __syncthreads();
    }
    if (t < SCAN_NB) {
        bsum[t] = s[t] - v;       // exclusive bucket prefix
        bcur[t] = s[t] - v;       // bucket fill cursor
    }
    if (t == 0) ptr[N_NODES] = E_MSG;
}

__global__ void __launch_bounds__(256) k_scan3(const int* __restrict__ cnt,
                                               const int* __restrict__ bsum,
                                               int* __restrict__ ptr,
                                               float* __restrict__ dinv) {
    __shared__ int s[256];
    int t = threadIdx.x;
    int n = blockIdx.x * 256 + t;
    int v = (n < N_NODES) ? cnt[n] : 0;
    s[t] = v;
    __syncthreads();
    for (int off = 1; off < 256; off <<= 1) {
        int u = (t >= off) ? s[t - off] : 0;
        __syncthreads();
        s[t] += u;
        __syncthreads();
    }
    if (n < N_NODES) {
        ptr[n] = bsum[blockIdx.x] + s[t] - v;
        dinv[n] = rsqrtf((float)v + 1.0f);
    }
}

// pass B: scatter (src,dst) into 256-node coarse buckets (line-local appends)
__global__ void k_bfill(const int* __restrict__ row, const int* __restrict__ col,
                        int* __restrict__ bcur, uint2* __restrict__ tmp) {
    int t = blockIdx.x * 256 + threadIdx.x;
    if (t < E_MSG) {
        int src = row[t], c = col[t];
        int pos = atomicAdd(&bcur[c >> 8], 1);
        tmp[pos] = uint2{(unsigned)src, (unsigned)c};
    }
}

// pass C: one block per bucket — LDS per-node cursors; elist writes stay in a
// ~16KB span (L2-line packed)
__global__ void __launch_bounds__(256) k_csort(const uint2* __restrict__ tmp,
                                               const int* __restrict__ bsum,
                                               const int* __restrict__ ptr,
                                               int* __restrict__ elist) {
    __shared__ int cur[256];
    int b = blockIdx.x;
    int n = (b << 8) + threadIdx.x;
    cur[threadIdx.x] = (n < N_NODES) ? ptr[n] : 0;
    __syncthreads();
    int start = bsum[b];
    int end = (b == SCAN_NB - 1) ? E_MSG : bsum[b + 1];
    for (int e = start + threadIdx.x; e < end; e += 256) {
        uint2 p = tmp[e];
        int pos = atomicAdd(&cur[p.y & 255], 1);
        elist[pos] = (int)p.x;
    }
}

// ---------------- gather-0 + relu + fused GCN-linear-1 ----------------
__global__ void __launch_bounds__(256) k_gather0(const unsigned short* __restrict__ zbf,
                                                 const int* __restrict__ ptr,
                                                 const int* __restrict__ elist,
                                                 const float* __restrict__ dinv,
                                                 const float* __restrict__ bias,
                                                 const float* __restrict__ Wc1,
                                                 unsigned short* __restrict__ zout) {
    __shared__ float hsh[4][64];
    int wv = threadIdx.x >> 6;
    int j = threadIdx.x & 63;
    int n = blockIdx.x * 4 + wv;
    int base = ptr[n];
    int end  = ptr[n + 1];
    float sum = bf2f(zbf[(size_t)n * 64 + j]);
    int k = base;
    for (; k + 16 <= end; k += 16) {
        int r[16];
#pragma unroll
        for (int q = 0; q < 16; q++) r[q] = elist[k + q];
        float v[16];
#pragma unroll
        for (int q = 0; q < 16; q++) v[q] = bf2f(zbf[(size_t)r[q] * 64 + j]);
        float s0 = ((v[0] + v[1]) + (v[2] + v[3])) + ((v[4] + v[5]) + (v[6] + v[7]));
        float s1 = ((v[8] + v[9]) + (v[10] + v[11])) + ((v[12] + v[13]) + (v[14] + v[15]));
        sum += s0 + s1;
    }
    for (; k + 4 <= end; k += 4) {
        int r0 = elist[k], r1 = elist[k + 1], r2 = elist[k + 2], r3 = elist[k + 3];
        float v0 = bf2f(zbf[(size_t)r0 * 64 + j]);
        float v1 = bf2f(zbf[(size_t)r1 * 64 + j]);
        float v2 = bf2f(zbf[(size_t)r2 * 64 + j]);
        float v3 = bf2f(zbf[(size_t)r3 * 64 + j]);
        sum += (v0 + v1) + (v2 + v3);
    }
    for (; k < end; k++)
        sum += bf2f(zbf[(size_t)elist[k] * 64 + j]);
    float h = fmaxf(dinv[n] * sum + bias[j], 0.0f);
    hsh[wv][j] = h;
    __syncthreads();

    float z = 0.0f;
#pragma unroll 16
    for (int kk = 0; kk < 64; kk++)
        z = fmaf(hsh[wv][kk], Wc1[kk * 64 + j], z);
    zout[(size_t)n * 64 + j] = f2bf(z * dinv[n]);
}

// ---------------- gather-1 -> h_enc (fp32 out + fp8x16 table) ----------------
__global__ void __launch_bounds__(256) k_gather1(const unsigned short* __restrict__ zbf,
                                                 const int* __restrict__ ptr,
                                                 const int* __restrict__ elist,
                                                 const float* __restrict__ dinv,
                                                 const float* __restrict__ bias,
                                                 unsigned char* __restrict__ henc8,
                                                 float* __restrict__ ofp) {
    int n = blockIdx.x * 4 + (threadIdx.x >> 6);
    int j = threadIdx.x & 63;
    int base = ptr[n];
    int end  = ptr[n + 1];
    float sum = bf2f(zbf[(size_t)n * 64 + j]);
    int k = base;
    for (; k + 16 <= end; k += 16) {
        int r[16];
#pragma unroll
        for (int q = 0; q < 16; q++) r[q] = elist[k + q];
        float v[16];
#pragma unroll
        for (int q = 0; q < 16; q++) v[q] = bf2f(zbf[(size_t)r[q] * 64 + j]);
        float s0 = ((v[0] + v[1]) + (v[2] + v[3])) + ((v[4] + v[5]) + (v[6] + v[7]));
        float s1 = ((v[8] + v[9]) + (v[10] + v[11])) + ((v[12] + v[13]) + (v[14] + v[15]));
        sum += s0 + s1;
    }
    for (; k + 4 <= end; k += 4) {
        int r0 = elist[k], r1 = elist[k + 1], r2 = elist[k + 2], r3 = elist[k + 3];
        float v0 = bf2f(zbf[(size_t)r0 * 64 + j]);
        float v1 = bf2f(zbf[(size_t)r1 * 64 + j]);
        float v2 = bf2f(zbf[(size_t)r2 * 64 + j]);
        float v3 = bf2f(zbf[(size_t)r3 * 64 + j]);
        sum += (v0 + v1) + (v2 + v3);
    }
    for (; k < end; k++)
        sum += bf2f(zbf[(size_t)elist[k] * 64 + j]);
    float v = dinv[n] * sum + bias[j];
    size_t t = (size_t)n * 64 + j;
    ofp[t] = v;
    henc8[t] = f2fp8(16.0f * v);
}

// ---------------- edge decoder (MFMA fp8, pipelined) ----------------
#define DEC_TPW 4
#define DEC_TILES (E_FULL / 16)

__global__ void __launch_bounds__(256) k_dec(const int* __restrict__ src,
                                             const int* __restrict__ dst,
                                             const unsigned char* __restrict__ h8,
                                             const float* __restrict__ ws,
                                             float* __restrict__ out) {
    int lane = threadIdx.x & 63;
    int wv = threadIdx.x >> 6;
    int m = lane & 15;
    int quad = lane >> 4;

    const unsigned char* fw = (const unsigned char*)(ws + OFF_FWD1);
    long bfr[4][4];
#pragma unroll
    for (int c = 0; c < 4; c++)
#pragma unroll
        for (int t = 0; t < 4; t++)
            bfr[c][t] = *reinterpret_cast<const long*>(fw + ((c * 4 + t) * 512 + lane * 8));

    float w2[4], b1v[4];
#pragma unroll
    for (int t = 0; t < 4; t++) {
        w2[t]  = ws[OFF_Wd2 + 16 * t + m];
        b1v[t] = ws[OFF_bd1 + 16 * t + m];
    }
    float b2 = ws[OFF_bd2];

    int tile0 = (blockIdx.x * 4 + wv) * DEC_TPW;
    int tc = min(tile0, DEC_TILES - 1);
    int s0 = src[tc * 16 + m], d0 = dst[tc * 16 + m];
    tc = min(tile0 + 1, DEC_TILES - 1);
    int s1 = src[tc * 16 + m], d1 = dst[tc * 16 + m];
    long A0[4];
#pragma unroll
    for (int c = 0; c < 4; c++) {
        int row = (c < 2) ? s0 : d0;
        A0[c] = *reinterpret_cast<const long*>(
            h8 + (size_t)row * 64 + (c & 1) * 32 + 8 * quad);
    }

    for (int i = 0; i < DEC_TPW; i++) {
        int tile = tile0 + i;
        int t2 = min(tile0 + i + 2, DEC_TILES - 1);
        int s2 = src[t2 * 16 + m], d2 = dst[t2 * 16 + m];
        long A1[4];
#pragma unroll
        for (int c = 0; c < 4; c++) {
            int row = (c < 2) ? s1 : d1;
            A1[c] = *reinterpret_cast<const long*>(
                h8 + (size_t)row * 64 + (c & 1) * 32 + 8 * quad);
        }
        f32x4 acc[4] = {f32x4{0,0,0,0}, f32x4{0,0,0,0}, f32x4{0,0,0,0}, f32x4{0,0,0,0}};
#pragma unroll
        for (int c = 0; c < 4; c++)
#pragma unroll
            for (int t = 0; t < 4; t++)
                acc[t] = __builtin_amdgcn_mfma_f32_16x16x32_fp8_fp8(A0[c], bfr[c][t], acc[t], 0, 0, 0);
        float sums[4];
#pragma unroll
        for (int r = 0; r < 4; r++) {
            float sv = 0.0f;
#pragma unroll
            for (int t = 0; t < 4; t++) {
                float v = fmaf(acc[t][r], 0.00390625f, b1v[t]);   // /256 un-scale
                float h = v * __builtin_amdgcn_rcpf(1.0f + __expf(-v));
                sv = fmaf(h, w2[t], sv);
            }
#pragma unroll
            for (int msk = 8; msk >= 1; msk >>= 1)
                sv += __shfl_xor(sv, msk, 64);
            sums[r] = sv;
        }
        if (m == 0 && tile < DEC_TILES) {
            int ebase = tile * 16 + 4 * quad;
#pragma unroll
            for (int r = 0; r < 4; r++) out[ebase + r] = sums[r] + b2;
        }
#pragma unroll
        for (int c = 0; c < 4; c++) A0[c] = A1[c];
        s1 = s2; d1 = d2;
    }
}

extern "C" void kernel_launch(void* const* d_in, const int* in_sizes, int n_in,
                              void* d_out, int out_size, void* d_ws, size_t ws_size,
                              hipStream_t stream) {
    if (n_in < 18) return;
    const void* x              = d_in[0];
    const int* edge_index      = (const int*)d_in[1];
    const int* full_edge_index = (const int*)d_in[2];
    const int* tsteps          = (const int*)d_in[3];
    float* ws = (float*)d_ws;
    float* out = (float*)d_out;

    int*   iws   = (int*)d_ws;
    int*   bsum  = iws + OFF_BSUM;
    int*   bcur  = iws + OFF_BCUR;
    int*   cnt   = iws + OFF_CNT;
    int*   ptr   = iws + OFF_PTR;
    int*   elist = iws + OFF_ELIST;
    uint2* tmp   = (uint2*)(iws + OFF_TMP2);
    unsigned short* zbf  = (unsigned short*)(ws + OFF_ZBF);
    unsigned short* zbf2 = (unsigned short*)(ws + OFF_ZBF2);
    unsigned char*  h8   = (unsigned char*)(ws + OFF_HENC8);

    CvtArgs ca;
    for (int i = 0; i < 14; i++) ca.src[i] = d_in[4 + i];

    // CSR build (by dst) + dinv — bucketed counting sort
    hipMemsetAsync(cnt, 0, (size_t)N_NODES * 4, stream);
    k_count<<<(E_MSG + 255) / 256, 256, 0, stream>>>(edge_index + E_MSG, cnt);
    k_scan1<<<SCAN_NB, 256, 0, stream>>>(cnt, bsum);
    k_scan2<<<1, 256, 0, stream>>>(bsum, bcur, ptr);
    k_scan3<<<SCAN_NB, 256, 0, stream>>>(cnt, bsum, ptr, ws + OFF_DINV);
    k_bfill<<<(E_MSG + 255) / 256, 256, 0, stream>>>(edge_index, edge_index + E_MSG,
                                                     bcur, tmp);
    k_csort<<<SCAN_NB, 256, 0, stream>>>(tmp, bsum, ptr, elist);

    // weights -> fp32, frag tables, t_emb table
    k_cvt<<<(W_TOTAL + 255) / 256, 256, 0, stream>>>(ca, ws);
    k_prep<<<80, 256, 0, stream>>>(ws);
    k_temb<<<T_STEPS, 64, 0, stream>>>(ws);

    // embedder + fused lin0 (h_embed -> d_out fp32; z0 -> zbf)
    k_embed<<<(N_NODES / 16 + 3) / 4, 256, 0, stream>>>(
        x, (const unsigned short*)d_in[4], tsteps, ws, out + E_FULL, zbf);

    // gather0 + relu + fused lin1: zbf -> zbf2
    k_gather0<<<N_NODES / 4, 256, 0, stream>>>(
        zbf, ptr, elist, ws + OFF_DINV, ws + OFF_bc0, ws + OFF_Wc1, zbf2);

    // gather1: zbf2 -> {out fp32, h8 fp8x16}
    k_gather1<<<N_NODES / 4, 256, 0, stream>>>(
        zbf2, ptr, elist, ws + OFF_DINV, ws + OFF_bc1, h8,
        out + E_FULL + (size_t)N_NODES * 64);

    // decoder (fp8 MFMA)
    int dec_blocks = (DEC_TILES + 4 * DEC_TPW - 1) / (4 * DEC_TPW);
    k_dec<<<dec_blocks, 256, 0, stream>>>(full_edge_index, full_edge_index + E_FULL,
                                          h8, ws, out);
}

// Round 11
// 323.675 us; speedup vs baseline: 2.3529x; 2.3529x over previous
//
#include <hip/hip_runtime.h>
#include <hip/hip_bf16.h>
#include <math.h>

#define N_NODES 50000
#define E_MSG   800000
#define E_FULL  1000000
#define IN_C    128
#define H_C     64
#define T_STEPS 128

// ---- workspace layout (in floats) ----
#define OFF_Win   0
#define OFF_bin   8192
#define OFF_Wt1   8256
#define OFF_bt1   24640
#define OFF_Wt2   24896
#define OFF_bt2   41280
#define OFF_Wc0   41344
#define OFF_bc0   45440
#define OFF_Wc1   45504
#define OFF_bc1   49600
#define OFF_Wd1   49664
#define OFF_bd1   57856
#define OFF_Wd2   57920
#define OFF_bd2   57984
#define W_TOTAL   57985
#define OFF_BSUM  58016                 // 256 ints (bucket exclusive prefixes)
#define OFF_BCUR  58272                 // 256 ints (bucket fill cursors)
#define OFF_FWD1  58624                 // 8192 fp8 bytes (16*Wd1 frag table)
#define OFF_FWIN  60672                 // 8192 bf16 (W_in frag table)
#define OFF_FWC0  64768                 // 4096 bf16 (Wc0 frag table)
#define OFF_TEMB  66816                 // 128*64 floats
#define OFF_DINV  75008                 // 50000 floats
#define OFF_CNT   125008                // 50000 ints
#define OFF_PTR   175008                // 50001 ints
#define OFF_ELIST 225010                // 800000 ints
#define OFF_TMP   1025010               // pad
#define OFF_TMP2  1025012               // 1.6M ints (800000 uint2), 8B aligned
#define OFF_ZBF   2625012               // 3.2M bf16 (z0)
#define OFF_ZBF2  4225012               // 3.2M bf16 (z1)
#define OFF_HENC8 5825012               // 3.2M fp8 bytes
// total 6,625,012 floats = 26.5 MB

#define SCAN_NB   ((N_NODES + 255) / 256)   // 196 buckets
#define BF_NB     196                        // bfill blocks
#define BF_CH     ((E_MSG + BF_NB - 1) / BF_NB)   // 4082 edges/block

typedef __attribute__((ext_vector_type(8))) short bf16x8;
typedef __attribute__((ext_vector_type(4))) float f32x4;

static __device__ __forceinline__ float bf2f(unsigned short u) {
    return __uint_as_float(((unsigned)u) << 16);
}
static __device__ __forceinline__ unsigned short f2bf(float f) {
    unsigned u = __float_as_uint(f);
    unsigned r = (u + 0x7fffu + ((u >> 16) & 1u)) >> 16;
    return (unsigned short)r;
}
// fp32 -> fp8 e4m3fn, RNE, clamp to +-448
static __device__ __forceinline__ unsigned char f2fp8(float f) {
    unsigned u = __float_as_uint(f);
    unsigned s = (u >> 24) & 0x80;
    float a = fminf(__uint_as_float(u & 0x7FFFFFFF), 448.0f);
    if (a < 0.015625f) {
        int qi = (int)rintf(a * 512.0f);
        return (unsigned char)(s | qi);
    }
    unsigned ua = __float_as_uint(a);
    int e = (int)((ua >> 23) & 0xFF) - 127;
    unsigned man = (ua & 0x7FFFFF) | 0x800000;
    unsigned r = man >> 20;
    unsigned rem = man & 0xFFFFF;
    if (rem > 0x80000u || (rem == 0x80000u && (r & 1))) r++;
    if (r == 16) { r = 8; e++; }
    if (e > 8) return (unsigned char)(s | 0x7E);
    return (unsigned char)(s | ((unsigned)(e + 7) << 3) | (r & 7));
}
static __device__ __forceinline__ bool detect_f32(const unsigned short* w, int* scnt) {
    if (threadIdx.x == 0) *scnt = 0;
    __syncthreads();
    int big = 0;
    for (int i = threadIdx.x; i < 2048; i += blockDim.x)
        if (fabsf(bf2f(w[2 * i])) > 0.5f) big++;
    atomicAdd(scnt, big);
    __syncthreads();
    return *scnt > 64;
}

// ---------------- weight conversion -> fp32, packed ----------------
struct CvtArgs { const void* src[14]; };

__global__ void k_cvt(CvtArgs a, float* ws) {
    __shared__ int scnt;
    bool f32 = detect_f32((const unsigned short*)a.src[0], &scnt);
    int t = blockIdx.x * 256 + threadIdx.x;
    if (t >= W_TOTAL) return;
    const int starts[14] = {OFF_Win, OFF_bin, OFF_Wt1, OFF_bt1, OFF_Wt2, OFF_bt2,
                            OFF_Wc0, OFF_bc0, OFF_Wc1, OFF_bc1, OFF_Wd1, OFF_bd1,
                            OFF_Wd2, OFF_bd2};
    int seg = 0;
#pragma unroll
    for (int i = 1; i < 14; i++)
        if (t >= starts[i]) seg = i;
    int off = t - starts[seg];
    ws[t] = f32 ? ((const float*)a.src[seg])[off]
                : bf2f(((const unsigned short*)a.src[seg])[off]);
}

// ---------------- MFMA B-fragment tables ----------------
__global__ void __launch_bounds__(256) k_prep(float* ws) {
    int idx = blockIdx.x * 256 + threadIdx.x;      // 0..20479
    int local, j, lane, ct, c, t, m, q;
    if (idx < 8192) {
        local = idx;
        j = local & 7; lane = (local >> 3) & 63; ct = local >> 9;
        c = ct >> 2; t = ct & 3; m = lane & 15; q = lane >> 4;
        ((unsigned char*)(ws + OFF_FWD1))[local] =
            f2fp8(16.0f * ws[OFF_Wd1 + (32 * c + 8 * q + j) * 64 + 16 * t + m]);
    } else if (idx < 16384) {
        local = idx - 8192;
        j = local & 7; lane = (local >> 3) & 63; ct = local >> 9;
        c = ct >> 2; t = ct & 3; m = lane & 15; q = lane >> 4;
        ((unsigned short*)(ws + OFF_FWIN))[local] =
            f2bf(ws[OFF_Win + (32 * c + 8 * q + j) * 64 + 16 * t + m]);
    } else if (idx < 20480) {
        local = idx - 16384;
        j = local & 7; lane = (local >> 3) & 63; ct = local >> 9;
        c = ct >> 2; t = ct & 3; m = lane & 15; q = lane >> 4;
        ((unsigned short*)(ws + OFF_FWC0))[local] =
            f2bf(ws[OFF_Wc0 + (32 * c + 8 * q + j) * 64 + 16 * t + m]);
    }
}

// ---------------- t_emb table ----------------
__global__ void __launch_bounds__(64) k_temb(float* ws) {
    const float* Wt1 = ws + OFF_Wt1;
    const float* bt1 = ws + OFF_bt1;
    const float* Wt2 = ws + OFF_Wt2;
    const float* bt2 = ws + OFF_bt2;
    float* temb = ws + OFF_TEMB;
    int t = blockIdx.x;
    int j = threadIdx.x;

    __shared__ float pe[64];
    __shared__ float us[256];

    float xt = (float)t * (4000.0f / 128.0f);
    float sc = -logf(10000.0f) / 31.0f;
    int idx = j & 31;
    float fr = __expf((float)idx * sc);
    float ang = xt * fr;
    pe[j] = (j < 32) ? sinf(ang) : cosf(ang);
    __syncthreads();

    float u[4];
#pragma unroll
    for (int q = 0; q < 4; q++) u[q] = bt1[q * 64 + j];
    for (int k = 0; k < 64; k++) {
        float p = pe[k];
#pragma unroll
        for (int q = 0; q < 4; q++)
            u[q] = fmaf(p, Wt1[k * 256 + q * 64 + j], u[q]);
    }
#pragma unroll
    for (int q = 0; q < 4; q++) {
        float uu = u[q];
        us[q * 64 + j] = uu * __builtin_amdgcn_rcpf(1.0f + __expf(-uu));
    }
    __syncthreads();

    float acc = bt2[j];
    for (int k = 0; k < 256; k++)
        acc = fmaf(us[k], Wt2[k * 64 + j], acc);
    temb[t * 64 + j] = acc;
}

// ---------------- embedder + fused GCN-linear-0 (MFMA x2) ----------------
__global__ void __launch_bounds__(256) k_embed(const void* __restrict__ xraw,
                                               const unsigned short* __restrict__ wdet,
                                               const int* __restrict__ tsteps,
                                               float* __restrict__ ws,
                                               float* __restrict__ out_hembed,
                                               unsigned short* __restrict__ zbf) {
    __shared__ int scnt;
    __shared__ unsigned short tl[4][16 * 64];
    bool f32 = detect_f32(wdet, &scnt);

    int lane = threadIdx.x & 63;
    int wv = threadIdx.x >> 6;
    int m = lane & 15, quad = lane >> 4;
    int wid = blockIdx.x * 4 + wv;
    if (wid > N_NODES / 16 - 1) wid = N_NODES / 16 - 1;   // clamp (dup work benign)
    int n0 = wid * 16;

    const unsigned short* fwin = (const unsigned short*)(ws + OFF_FWIN);
    const unsigned short* fwc0 = (const unsigned short*)(ws + OFF_FWC0);

    bf16x8 bI[4][4];
#pragma unroll
    for (int c = 0; c < 4; c++)
#pragma unroll
        for (int t = 0; t < 4; t++)
            bI[c][t] = *reinterpret_cast<const bf16x8*>(fwin + (c * 4 + t) * 512 + lane * 8);

    f32x4 acc[4] = {f32x4{0,0,0,0}, f32x4{0,0,0,0}, f32x4{0,0,0,0}, f32x4{0,0,0,0}};
#pragma unroll
    for (int c = 0; c < 4; c++) {
        bf16x8 a;
        if (f32) {
            const float* xp = (const float*)xraw + (size_t)(n0 + m) * 128 + 32 * c + 8 * quad;
            float4 v0 = *reinterpret_cast<const float4*>(xp);
            float4 v1 = *reinterpret_cast<const float4*>(xp + 4);
            a[0] = (short)f2bf(v0.x); a[1] = (short)f2bf(v0.y);
            a[2] = (short)f2bf(v0.z); a[3] = (short)f2bf(v0.w);
            a[4] = (short)f2bf(v1.x); a[5] = (short)f2bf(v1.y);
            a[6] = (short)f2bf(v1.z); a[7] = (short)f2bf(v1.w);
        } else {
            a = *reinterpret_cast<const bf16x8*>(
                (const unsigned short*)xraw + (size_t)(n0 + m) * 128 + 32 * c + 8 * quad);
        }
#pragma unroll
        for (int t = 0; t < 4; t++)
            acc[t] = __builtin_amdgcn_mfma_f32_16x16x32_bf16(a, bI[c][t], acc[t], 0, 0, 0);
    }

    int tn[4];
#pragma unroll
    for (int r = 0; r < 4; r++) tn[r] = tsteps[n0 + 4 * quad + r];
    const float* temb = ws + OFF_TEMB;
#pragma unroll
    for (int t = 0; t < 4; t++) {
        int ch = 16 * t + m;
        float bj = ws[OFF_bin + ch];
#pragma unroll
        for (int r = 0; r < 4; r++) {
            int node = n0 + 4 * quad + r;
            float v = acc[t][r] + bj + temb[tn[r] * 64 + ch];
            out_hembed[(size_t)node * 64 + ch] = v;
            tl[wv][(4 * quad + r) * 64 + ch] = f2bf(v);
        }
    }
    __syncthreads();

    bf16x8 bC[2][4];
#pragma unroll
    for (int c = 0; c < 2; c++)
#pragma unroll
        for (int t = 0; t < 4; t++)
            bC[c][t] = *reinterpret_cast<const bf16x8*>(fwc0 + (c * 4 + t) * 512 + lane * 8);

    f32x4 az[4] = {f32x4{0,0,0,0}, f32x4{0,0,0,0}, f32x4{0,0,0,0}, f32x4{0,0,0,0}};
#pragma unroll
    for (int c = 0; c < 2; c++) {
        bf16x8 a2 = *reinterpret_cast<const bf16x8*>(&tl[wv][m * 64 + 32 * c + 8 * quad]);
#pragma unroll
        for (int t = 0; t < 4; t++)
            az[t] = __builtin_amdgcn_mfma_f32_16x16x32_bf16(a2, bC[c][t], az[t], 0, 0, 0);
    }
    const float* dinv = ws + OFF_DINV;
    float dv[4];
#pragma unroll
    for (int r = 0; r < 4; r++) dv[r] = dinv[n0 + 4 * quad + r];
#pragma unroll
    for (int t = 0; t < 4; t++) {
        int ch = 16 * t + m;
#pragma unroll
        for (int r = 0; r < 4; r++)
            zbf[(size_t)(n0 + 4 * quad + r) * 64 + ch] = f2bf(az[t][r] * dv[r]);
    }
}

// ---------------- CSR build ----------------
__global__ void k_count(const int* __restrict__ col, int* __restrict__ cnt) {
    int t = blockIdx.x * 256 + threadIdx.x;
    if (t < E_MSG) atomicAdd(&cnt[col[t]], 1);
}

__global__ void __launch_bounds__(256) k_scan1(const int* __restrict__ cnt,
                                               int* __restrict__ bsum) {
    __shared__ int s[256];
    int n = blockIdx.x * 256 + threadIdx.x;
    s[threadIdx.x] = (n < N_NODES) ? cnt[n] : 0;
    __syncthreads();
    for (int off = 128; off > 0; off >>= 1) {
        if (threadIdx.x < off) s[threadIdx.x] += s[threadIdx.x + off];
        __syncthreads();
    }
    if (threadIdx.x == 0) bsum[blockIdx.x] = s[0];
}

__global__ void __launch_bounds__(256) k_scan2(int* __restrict__ bsum,
                                               int* __restrict__ bcur,
                                               int* __restrict__ ptr) {
    __shared__ int s[256];
    int t = threadIdx.x;
    int v = (t < SCAN_NB) ? bsum[t] : 0;
    s[t] = v;
    __syncthreads();
    for (int off = 1; off < 256; off <<= 1) {
        int u = (t >= off) ? s[t - off] : 0;
        __syncthreads();
        s[t] += u;
        __syncthreads();
    }
    if (t < SCAN_NB) {
        bsum[t] = s[t] - v;       // exclusive bucket prefix
        bcur[t] = s[t] - v;       // bucket fill cursor
    }
    if (t == 0) ptr[N_NODES] = E_MSG;
}

__global__ void __launch_bounds__(256) k_scan3(const int* __restrict__ cnt,
                                               const int* __restrict__ bsum,
                                               int* __restrict__ ptr,
                                               float* __restrict__ dinv) {
    __shared__ int s[256];
    int t = threadIdx.x;
    int n = blockIdx.x * 256 + t;
    int v = (n < N_NODES) ? cnt[n] : 0;
    s[t] = v;
    __syncthreads();
    for (int off = 1; off < 256; off <<= 1) {
        int u = (t >= off) ? s[t - off] : 0;
        __syncthreads();
        s[t] += u;
        __syncthreads();
    }
    if (n < N_NODES) {
        ptr[n] = bsum[blockIdx.x] + s[t] - v;
        dinv[n] = rsqrtf((float)v + 1.0f);
    }
}

// pass B (fixed): per-block LDS histogram + ONE reservation atomic per
// (block, bucket) — kills the 196-hot-address serialization of round 10.
__global__ void __launch_bounds__(256) k_bfill(const int* __restrict__ row,
                                               const int* __restrict__ col,
                                               int* __restrict__ bcur,
                                               uint2* __restrict__ tmp) {
    __shared__ int hist[SCAN_NB];
    __shared__ int basew[SCAN_NB];
    int b = blockIdx.x;
    int lo = b * BF_CH;
    int hi = lo + BF_CH; if (hi > E_MSG) hi = E_MSG;
    for (int i = threadIdx.x; i < SCAN_NB; i += 256) hist[i] = 0;
    __syncthreads();
    for (int e = lo + threadIdx.x; e < hi; e += 256)
        atomicAdd(&hist[col[e] >> 8], 1);
    __syncthreads();
    for (int i = threadIdx.x; i < SCAN_NB; i += 256) {
        int c = hist[i];
        basew[i] = (c > 0) ? atomicAdd(&bcur[i], c) : 0;
    }
    __syncthreads();
    for (int i = threadIdx.x; i < SCAN_NB; i += 256) hist[i] = 0;  // reuse as cursor
    __syncthreads();
    for (int e = lo + threadIdx.x; e < hi; e += 256) {
        int src = row[e], c = col[e];
        int bk = c >> 8;
        int off = atomicAdd(&hist[bk], 1);
        tmp[basew[bk] + off] = uint2{(unsigned)src, (unsigned)c};
    }
}

// pass C: one block per bucket — LDS per-node cursors; elist writes stay in a
// ~16KB span (L2-line packed)
__global__ void __launch_bounds__(256) k_csort(const uint2* __restrict__ tmp,
                                               const int* __restrict__ bsum,
                                               const int* __restrict__ ptr,
                                               int* __restrict__ elist) {
    __shared__ int cur[256];
    int b = blockIdx.x;
    int n = (b << 8) + threadIdx.x;
    cur[threadIdx.x] = (n < N_NODES) ? ptr[n] : 0;
    __syncthreads();
    int start = bsum[b];
    int end = (b == SCAN_NB - 1) ? E_MSG : bsum[b + 1];
    for (int e = start + threadIdx.x; e < end; e += 256) {
        uint2 p = tmp[e];
        int pos = atomicAdd(&cur[p.y & 255], 1);
        elist[pos] = (int)p.x;
    }
}

// ---------------- gather-0 + relu + fused GCN-linear-1 ----------------
__global__ void __launch_bounds__(256) k_gather0(const unsigned short* __restrict__ zbf,
                                                 const int* __restrict__ ptr,
                                                 const int* __restrict__ elist,
                                                 const float* __restrict__ dinv,
                                                 const float* __restrict__ bias,
                                                 const float* __restrict__ Wc1,
                                                 unsigned short* __restrict__ zout) {
    __shared__ float hsh[4][64];
    int wv = threadIdx.x >> 6;
    int j = threadIdx.x & 63;
    int n = blockIdx.x * 4 + wv;
    int base = ptr[n];
    int end  = ptr[n + 1];
    float sum = bf2f(zbf[(size_t)n * 64 + j]);
    int k = base;
    for (; k + 16 <= end; k += 16) {
        int r[16];
#pragma unroll
        for (int q = 0; q < 16; q++) r[q] = elist[k + q];
        float v[16];
#pragma unroll
        for (int q = 0; q < 16; q++) v[q] = bf2f(zbf[(size_t)r[q] * 64 + j]);
        float s0 = ((v[0] + v[1]) + (v[2] + v[3])) + ((v[4] + v[5]) + (v[6] + v[7]));
        float s1 = ((v[8] + v[9]) + (v[10] + v[11])) + ((v[12] + v[13]) + (v[14] + v[15]));
        sum += s0 + s1;
    }
    for (; k + 4 <= end; k += 4) {
        int r0 = elist[k], r1 = elist[k + 1], r2 = elist[k + 2], r3 = elist[k + 3];
        float v0 = bf2f(zbf[(size_t)r0 * 64 + j]);
        float v1 = bf2f(zbf[(size_t)r1 * 64 + j]);
        float v2 = bf2f(zbf[(size_t)r2 * 64 + j]);
        float v3 = bf2f(zbf[(size_t)r3 * 64 + j]);
        sum += (v0 + v1) + (v2 + v3);
    }
    for (; k < end; k++)
        sum += bf2f(zbf[(size_t)elist[k] * 64 + j]);
    float h = fmaxf(dinv[n] * sum + bias[j], 0.0f);
    hsh[wv][j] = h;
    __syncthreads();

    float z = 0.0f;
#pragma unroll 16
    for (int kk = 0; kk < 64; kk++)
        z = fmaf(hsh[wv][kk], Wc1[kk * 64 + j], z);
    zout[(size_t)n * 64 + j] = f2bf(z * dinv[n]);
}

// ---------------- gather-1 -> h_enc (fp32 out + fp8x16 table) ----------------
__global__ void __launch_bounds__(256) k_gather1(const unsigned short* __restrict__ zbf,
                                                 const int* __restrict__ ptr,
                                                 const int* __restrict__ elist,
                                                 const float* __restrict__ dinv,
                                                 const float* __restrict__ bias,
                                                 unsigned char* __restrict__ henc8,
                                                 float* __restrict__ ofp) {
    int n = blockIdx.x * 4 + (threadIdx.x >> 6);
    int j = threadIdx.x & 63;
    int base = ptr[n];
    int end  = ptr[n + 1];
    float sum = bf2f(zbf[(size_t)n * 64 + j]);
    int k = base;
    for (; k + 16 <= end; k += 16) {
        int r[16];
#pragma unroll
        for (int q = 0; q < 16; q++) r[q] = elist[k + q];
        float v[16];
#pragma unroll
        for (int q = 0; q < 16; q++) v[q] = bf2f(zbf[(size_t)r[q] * 64 + j]);
        float s0 = ((v[0] + v[1]) + (v[2] + v[3])) + ((v[4] + v[5]) + (v[6] + v[7]));
        float s1 = ((v[8] + v[9]) + (v[10] + v[11])) + ((v[12] + v[13]) + (v[14] + v[15]));
        sum += s0 + s1;
    }
    for (; k + 4 <= end; k += 4) {
        int r0 = elist[k], r1 = elist[k + 1], r2 = elist[k + 2], r3 = elist[k + 3];
        float v0 = bf2f(zbf[(size_t)r0 * 64 + j]);
        float v1 = bf2f(zbf[(size_t)r1 * 64 + j]);
        float v2 = bf2f(zbf[(size_t)r2 * 64 + j]);
        float v3 = bf2f(zbf[(size_t)r3 * 64 + j]);
        sum += (v0 + v1) + (v2 + v3);
    }
    for (; k < end; k++)
        sum += bf2f(zbf[(size_t)elist[k] * 64 + j]);
    float v = dinv[n] * sum + bias[j];
    size_t t = (size_t)n * 64 + j;
    ofp[t] = v;
    henc8[t] = f2fp8(16.0f * v);
}

// ---------------- edge decoder (MFMA fp8, pipelined) ----------------
#define DEC_TPW 4
#define DEC_TILES (E_FULL / 16)

__global__ void __launch_bounds__(256) k_dec(const int* __restrict__ src,
                                             const int* __restrict__ dst,
                                             const unsigned char* __restrict__ h8,
                                             const float* __restrict__ ws,
                                             float* __restrict__ out) {
    int lane = threadIdx.x & 63;
    int wv = threadIdx.x >> 6;
    int m = lane & 15;
    int quad = lane >> 4;

    const unsigned char* fw = (const unsigned char*)(ws + OFF_FWD1);
    long bfr[4][4];
#pragma unroll
    for (int c = 0; c < 4; c++)
#pragma unroll
        for (int t = 0; t < 4; t++)
            bfr[c][t] = *reinterpret_cast<const long*>(fw + ((c * 4 + t) * 512 + lane * 8));

    float w2[4], b1v[4];
#pragma unroll
    for (int t = 0; t < 4; t++) {
        w2[t]  = ws[OFF_Wd2 + 16 * t + m];
        b1v[t] = ws[OFF_bd1 + 16 * t + m];
    }
    float b2 = ws[OFF_bd2];

    int tile0 = (blockIdx.x * 4 + wv) * DEC_TPW;
    int tc = min(tile0, DEC_TILES - 1);
    int s0 = src[tc * 16 + m], d0 = dst[tc * 16 + m];
    tc = min(tile0 + 1, DEC_TILES - 1);
    int s1 = src[tc * 16 + m], d1 = dst[tc * 16 + m];
    long A0[4];
#pragma unroll
    for (int c = 0; c < 4; c++) {
        int row = (c < 2) ? s0 : d0;
        A0[c] = *reinterpret_cast<const long*>(
            h8 + (size_t)row * 64 + (c & 1) * 32 + 8 * quad);
    }

    for (int i = 0; i < DEC_TPW; i++) {
        int tile = tile0 + i;
        int t2 = min(tile0 + i + 2, DEC_TILES - 1);
        int s2 = src[t2 * 16 + m], d2 = dst[t2 * 16 + m];
        long A1[4];
#pragma unroll
        for (int c = 0; c < 4; c++) {
            int row = (c < 2) ? s1 : d1;
            A1[c] = *reinterpret_cast<const long*>(
                h8 + (size_t)row * 64 + (c & 1) * 32 + 8 * quad);
        }
        f32x4 acc[4] = {f32x4{0,0,0,0}, f32x4{0,0,0,0}, f32x4{0,0,0,0}, f32x4{0,0,0,0}};
#pragma unroll
        for (int c = 0; c < 4; c++)
#pragma unroll
            for (int t = 0; t < 4; t++)
                acc[t] = __builtin_amdgcn_mfma_f32_16x16x32_fp8_fp8(A0[c], bfr[c][t], acc[t], 0, 0, 0);
        float sums[4];
#pragma unroll
        for (int r = 0; r < 4; r++) {
            float sv = 0.0f;
#pragma unroll
            for (int t = 0; t < 4; t++) {
                float v = fmaf(acc[t][r], 0.00390625f, b1v[t]);   // /256 un-scale
                float h = v * __builtin_amdgcn_rcpf(1.0f + __expf(-v));
                sv = fmaf(h, w2[t], sv);
            }
#pragma unroll
            for (int msk = 8; msk >= 1; msk >>= 1)
                sv += __shfl_xor(sv, msk, 64);
            sums[r] = sv;
        }
        if (m == 0 && tile < DEC_TILES) {
            int ebase = tile * 16 + 4 * quad;
#pragma unroll
            for (int r = 0; r < 4; r++) out[ebase + r] = sums[r] + b2;
        }
#pragma unroll
        for (int c = 0; c < 4; c++) A0[c] = A1[c];
        s1 = s2; d1 = d2;
    }
}

extern "C" void kernel_launch(void* const* d_in, const int* in_sizes, int n_in,
                              void* d_out, int out_size, void* d_ws, size_t ws_size,
                              hipStream_t stream) {
    if (n_in < 18) return;
    const void* x              = d_in[0];
    const int* edge_index      = (const int*)d_in[1];
    const int* full_edge_index = (const int*)d_in[2];
    const int* tsteps          = (const int*)d_in[3];
    float* ws = (float*)d_ws;
    float* out = (float*)d_out;

    int*   iws   = (int*)d_ws;
    int*   bsum  = iws + OFF_BSUM;
    int*   bcur  = iws + OFF_BCUR;
    int*   cnt   = iws + OFF_CNT;
    int*   ptr   = iws + OFF_PTR;
    int*   elist = iws + OFF_ELIST;
    uint2* tmp   = (uint2*)(iws + OFF_TMP2);
    unsigned short* zbf  = (unsigned short*)(ws + OFF_ZBF);
    unsigned short* zbf2 = (unsigned short*)(ws + OFF_ZBF2);
    unsigned char*  h8   = (unsigned char*)(ws + OFF_HENC8);

    CvtArgs ca;
    for (int i = 0; i < 14; i++) ca.src[i] = d_in[4 + i];

    // CSR build (by dst) + dinv — bucketed counting sort
    hipMemsetAsync(cnt, 0, (size_t)N_NODES * 4, stream);
    k_count<<<(E_MSG + 255) / 256, 256, 0, stream>>>(edge_index + E_MSG, cnt);
    k_scan1<<<SCAN_NB, 256, 0, stream>>>(cnt, bsum);
    k_scan2<<<1, 256, 0, stream>>>(bsum, bcur, ptr);
    k_scan3<<<SCAN_NB, 256, 0, stream>>>(cnt, bsum, ptr, ws + OFF_DINV);
    k_bfill<<<BF_NB, 256, 0, stream>>>(edge_index, edge_index + E_MSG, bcur, tmp);
    k_csort<<<SCAN_NB, 256, 0, stream>>>(tmp, bsum, ptr, elist);

    // weights -> fp32, frag tables, t_emb table
    k_cvt<<<(W_TOTAL + 255) / 256, 256, 0, stream>>>(ca, ws);
    k_prep<<<80, 256, 0, stream>>>(ws);
    k_temb<<<T_STEPS, 64, 0, stream>>>(ws);

    // embedder + fused lin0 (h_embed -> d_out fp32; z0 -> zbf)
    k_embed<<<(N_NODES / 16 + 3) / 4, 256, 0, stream>>>(
        x, (const unsigned short*)d_in[4], tsteps, ws, out + E_FULL, zbf);

    // gather0 + relu + fused lin1: zbf -> zbf2
    k_gather0<<<N_NODES / 4, 256, 0, stream>>>(
        zbf, ptr, elist, ws + OFF_DINV, ws + OFF_bc0, ws + OFF_Wc1, zbf2);

    // gather1: zbf2 -> {out fp32, h8 fp8x16}
    k_gather1<<<N_NODES / 4, 256, 0, stream>>>(
        zbf2, ptr, elist, ws + OFF_DINV, ws + OFF_bc1, h8,
        out + E_FULL + (size_t)N_NODES * 64);

    // decoder (fp8 MFMA)
    int dec_blocks = (DEC_TILES + 4 * DEC_TPW - 1) / (4 * DEC_TPW);
    k_dec<<<dec_blocks, 256, 0, stream>>>(full_edge_index, full_edge_index + E_FULL,
                                          h8, ws, out);
}